// Round 21
// baseline (163.164 us; speedup 1.0000x reference)
//
#include <hip/hip_runtime.h>
#include <hip/hip_bf16.h>

// AttentionSeparateQKV: B=16 N=1024 D=768 H=12 HD=64, V = K-projection (reference bug kept).
// R21 = R18 (best, 161.7us; R19 KVBLK=128 and R20 QBLK=64 both lost to occupancy) with the
// attn t-loop unrolled x2 (compile-time LDS buffer offsets -> immediate folding) + hoisted
// loop-invariant address arithmetic + running staging pointers. Semantically R18-identical.

#define DEV static __device__ __forceinline__

typedef __attribute__((ext_vector_type(8)))  short  short8;
typedef __attribute__((ext_vector_type(4)))  short  short4v;
typedef __attribute__((ext_vector_type(4)))  float  f32x4;
typedef __attribute__((ext_vector_type(16))) float  f32x16;
typedef __attribute__((ext_vector_type(4)))  unsigned short ushort4v;
typedef __attribute__((ext_vector_type(8)))  unsigned short ushort8v;
typedef __attribute__((ext_vector_type(4)))  unsigned int   u32x4;

#define QSCALE 0.180336880f   // 0.125 * log2(e): logits in log2 domain

DEV unsigned short f2bf(float x) {
  unsigned int u = __float_as_uint(x);
  u = u + 0x7fffu + ((u >> 16) & 1u);   // RNE, inputs finite
  return (unsigned short)(u >> 16);
}

DEV float exp2v(float x) {              // v_exp_f32: D = 2^S0 (pure, CSE-able)
  float r;
  asm("v_exp_f32 %0, %1" : "=v"(r) : "v"(x));
  return r;
}

DEV unsigned cvtpk(float a, float b) {  // lo = bf(a), hi = bf(b); RNE (R3-proven)
  unsigned r;
  asm("v_cvt_pk_bf16_f32 %0, %1, %2" : "=v"(r) : "v"(a), "v"(b));
  return r;
}

#define GLOAD_LDS16(g, l)                                                     \
  __builtin_amdgcn_global_load_lds(                                           \
      (const __attribute__((address_space(1))) void*)(g),                     \
      (__attribute__((address_space(3))) void*)(l), 16, 0, 0)

// ---------------- merged prep: x cvt (8/thread) + weight cvts + bias stack ----------------
// blocks [0,576): Wq; [576,1152): Wk; [1152,1728): Wp; [1728,1734): bqk; [1734,7878): x.
__global__ __launch_bounds__(256) void k_prep(const float* __restrict__ x,
                                              const float* __restrict__ Wq,
                                              const float* __restrict__ Wk,
                                              const float* __restrict__ Wp,
                                              const float* __restrict__ bq,
                                              const float* __restrict__ bk,
                                              unsigned short* __restrict__ xb,
                                              unsigned short* __restrict__ wqb,
                                              unsigned short* __restrict__ wkb,
                                              unsigned short* __restrict__ wpb,
                                              float* __restrict__ bqk) {
  int blk = blockIdx.x;
  if (blk < 1728) {
    const float* src = (blk < 576) ? Wq : (blk < 1152) ? Wk : Wp;
    unsigned short* dst = (blk < 576) ? wqb : (blk < 1152) ? wkb : wpb;
    int i = (blk % 576) * 256 + threadIdx.x;    // 576*256 = 768*768/4 exactly
    f32x4 v = *(const f32x4*)(src + (size_t)i * 4);
    ushort4v o;
    o[0] = f2bf(v[0]); o[1] = f2bf(v[1]); o[2] = f2bf(v[2]); o[3] = f2bf(v[3]);
    *(ushort4v*)(dst + (size_t)i * 4) = o;
  } else if (blk < 1734) {
    int i = (blk - 1728) * 256 + threadIdx.x;
    if (i < 768) bqk[i] = bq[i];
    else if (i < 1536) bqk[i] = bk[i - 768];
  } else {
    // x: 16384*768 f32 = 1,572,864 8-elem units = 6144 blocks exactly
    size_t i = (size_t)(blk - 1734) * 256 + threadIdx.x;
    const f32x4* src = (const f32x4*)(x + i * 8);
    f32x4 a = src[0], b4 = src[1];
    ushort8v o;
    o[0] = f2bf(a[0]);  o[1] = f2bf(a[1]);  o[2] = f2bf(a[2]);  o[3] = f2bf(a[3]);
    o[4] = f2bf(b4[0]); o[5] = f2bf(b4[1]); o[6] = f2bf(b4[2]); o[7] = f2bf(b4[3]);
    *(ushort8v*)(xb + i * 8) = o;
  }
}

// ---------------- GEMM: C = (A[M,K] * W[N,K]^T + bias[N]) ----------------
// bf16 A (R12-exact). MODE 0: fp32 out, row stride N. MODE 2: QK-fused bf16 out —
// cols [0,768) -> Cv scaled QSCALE (Q, log2 domain); [768,1536) -> K buffer AND kT2
// (kT2[bh][n/32][hd][n%32], transpose fused: 4 contiguous bf16 per (m,n) pair).
template <int MODE>
__global__ __launch_bounds__(256) void k_gemm_bt(const unsigned short* __restrict__ A,
                                                 const unsigned short* __restrict__ W,
                                                 const float* __restrict__ bias,
                                                 void* __restrict__ Cv,
                                                 unsigned short* __restrict__ kT2g,
                                                 int M, int N, int K) {
  __shared__ char lds[32768];
  char* ldsA = lds;
  char* ldsB = lds + 16384;
  const int tid  = threadIdx.x;
  const int wid  = tid >> 6;
  const int lane = tid & 63;
  const int row0 = blockIdx.x * 128;
  const int col0 = blockIdx.y * 128;
  const int wr = (wid >> 1) * 64;
  const int wc = (wid & 1) * 64;
  const int lr = lane & 15;
  const int lg = lane >> 4;

  f32x4 acc[4][4];
#pragma unroll
  for (int m = 0; m < 4; ++m)
#pragma unroll
    for (int n = 0; n < 4; ++n)
#pragma unroll
      for (int r = 0; r < 4; ++r) acc[m][n][r] = 0.f;

  for (int kt = 0; kt < K; kt += 64) {
    __syncthreads();
#pragma unroll
    for (int p = 0; p < 4; ++p) {
      int c = p * 256 + tid;               // 16B chunk id, 0..1023
      int r  = c >> 3;
      int cb = ((c & 7) << 4) ^ ((r & 7) << 4);
      const char* ga = (const char*)(A + (size_t)(row0 + r) * K + kt) + cb;
      GLOAD_LDS16(ga, ldsA + c * 16);
      const char* gb = (const char*)(W + (size_t)(col0 + r) * K + kt) + cb;
      GLOAD_LDS16(gb, ldsB + c * 16);
    }
    asm volatile("s_waitcnt vmcnt(0)" ::: "memory");
    __syncthreads();
#pragma unroll
    for (int kk = 0; kk < 2; ++kk) {
      short8 af[4], bf[4];
#pragma unroll
      for (int m = 0; m < 4; ++m) {
        int row = wr + m * 16 + lr;
        int a   = row * 128 + ((kk * 64 + lg * 16) ^ ((row & 7) << 4));
        af[m] = *(const short8*)(ldsA + a);
        int col = wc + m * 16 + lr;
        int b   = col * 128 + ((kk * 64 + lg * 16) ^ ((col & 7) << 4));
        bf[m] = *(const short8*)(ldsB + b);
      }
#pragma unroll
      for (int m = 0; m < 4; ++m)
#pragma unroll
        for (int n = 0; n < 4; ++n)
          acc[m][n] = __builtin_amdgcn_mfma_f32_16x16x32_bf16(af[m], bf[n], acc[m][n], 0, 0, 0);
    }
  }

  const int r0g = row0 + wr + lg * 4;
  const int c0g = col0 + wc + lr;
  float bv[4];
#pragma unroll
  for (int n = 0; n < 4; ++n) bv[n] = bias[c0g + n * 16];

  if constexpr (MODE == 2) {
    const bool kh = (col0 >= 768);
    unsigned short* dst = (unsigned short*)Cv + (kh ? ((size_t)16384 * 768 - 768) : 0);
    const float sc = kh ? 1.0f : QSCALE;
#pragma unroll
    for (int m = 0; m < 4; ++m)
#pragma unroll
      for (int n = 0; n < 4; ++n) {
        ushort4v t4;
#pragma unroll
        for (int r = 0; r < 4; ++r) {
          float v = (acc[m][n][r] + bv[n]) * sc;
          unsigned short bfv = f2bf(v);
          dst[(size_t)(r0g + m * 16 + r) * 768 + (c0g + n * 16)] = bfv;
          t4[r] = bfv;
        }
        if (kh) {
          // transpose-fused kT2 store: rows rowb..rowb+3 (n dim), col = head dim
          int hd2  = c0g + n * 16 - 768;     // 0..767: h = hd2>>6, hd = hd2&63
          int rowb = r0g + m * 16;           // multiple of 4 -> nn&31 stays in-block
          int b_ = rowb >> 10, nn = rowb & 1023;
          size_t kbase = ((((size_t)(b_ * 12 + (hd2 >> 6)) * 32 + (nn >> 5)) * 64
                           + (hd2 & 63)) * 32 + (nn & 31));
          *(ushort4v*)(kT2g + kbase) = t4;
        }
      }
  } else {
#pragma unroll
    for (int m = 0; m < 4; ++m)
#pragma unroll
      for (int n = 0; n < 4; ++n)
#pragma unroll
        for (int r = 0; r < 4; ++r) {
          float v = acc[m][n][r] + bv[n];
          ((float*)Cv)[(size_t)(r0g + m * 16 + r) * N + (c0g + n * 16)] = v;
        }
  }
}

// ---------------- Flash attention (V = K; q pre-scaled by 0.125*log2e) ----------------
// KVBLK=64 (R18-proven). t-loop unrolled x2: LDS buffer offsets are compile-time;
// per-lane address arithmetic hoisted. Un-normalized p = 2^s; lsum via ones-MFMA.
__global__ __launch_bounds__(256) void k_attn(const unsigned short* __restrict__ qg,
                                              const unsigned short* __restrict__ kg,
                                              const unsigned short* __restrict__ kT2,
                                              unsigned short* __restrict__ og) {
  __shared__ char lds[32768];           // 2 x 16KB staging dbuf; epilogue reuses [0,18432)
  const int tid  = threadIdx.x;
  const int w    = tid >> 6;
  const int lane = tid & 63;
  const int q32  = lane & 31;
  const int hi   = lane >> 5;
  // XCD swizzle: 8 qc-blocks of each bh land on one XCD (grid 1536 = 8*192)
  const int blk  = (blockIdx.x & 7) * 192 + (blockIdx.x >> 3);
  const int qc   = blk & 7;
  const int bh   = blk >> 3;
  const int h = bh % 12, b = bh / 12;
  const int qbase = qc * 128 + w * 32;

  const unsigned short* Qp = qg + (size_t)(b * 1024 + qbase + q32) * 768 + h * 64;
  short8 qf[4];
#pragma unroll
  for (int c = 0; c < 4; ++c) qf[c] = *(const short8*)(Qp + c * 16 + hi * 8);

  // ones A-frag for the lsum MFMA (bf16 1.0 = 0x3F80)
  short8 ones;
#pragma unroll
  for (int j = 0; j < 8; ++j) ones[j] = (short)0x3F80;

  const int sr = tid >> 3, sp = tid & 7;                     // Kt: row, phys slot
  const unsigned short* ksrc = kg + (size_t)(b * 1024 + sr) * 768 + h * 64 + ((sp ^ (sr & 7)) << 3);
  const int vh = tid >> 2, vp = tid & 3;                     // Vt: hd, phys slot
  const unsigned short* vsrc = kT2 + (size_t)bh * 65536 + (size_t)vh * 32 + ((vp ^ ((vh >> 1) & 3)) << 3);

  f32x16 o0, o1, lacc, zro;
#pragma unroll
  for (int r = 0; r < 16; ++r) { o0[r] = 0.f; o1[r] = 0.f; lacc[r] = 0.f; zro[r] = 0.f; }

  // prologue: stage iter 0 (K0,K1,V0,V1) into buf 0
  GLOAD_LDS16(ksrc,          lds + tid * 16);
  GLOAD_LDS16(ksrc + 24576,  lds + 4096 + tid * 16);
  GLOAD_LDS16(vsrc,          lds + 8192 + tid * 16);
  GLOAD_LDS16(vsrc + 2048,   lds + 12288 + tid * 16);

  // running staging pointers (next K-pair / V-pair to stage = iter 1)
  const unsigned short* kstage = ksrc + 49152;
  const unsigned short* vstage = vsrc + 4096;

  // hoisted loop-invariant fragment offsets
  const int kfo0 = q32 * 128;
  const int vswz = (q32 >> 1) & 3;
  int kaddr[4];
#pragma unroll
  for (int c = 0; c < 4; ++c) kaddr[c] = kfo0 + (((c * 2 + hi) ^ (q32 & 7)) << 4);
  int vaddr[2][2];
#pragma unroll
  for (int f = 0; f < 2; ++f)
#pragma unroll
    for (int s2 = 0; s2 < 2; ++s2)
      vaddr[s2][f] = (f * 32 + q32) * 64 + (((s2 * 2 + hi) ^ vswz) << 4);

#define ATTN_STEP(BO, BN, DOSTAGE)                                            \
  {                                                                           \
    asm volatile("s_waitcnt vmcnt(0)" ::: "memory");                          \
    __syncthreads();                                                          \
    if (DOSTAGE) {                                                            \
      GLOAD_LDS16(kstage,         lds + (BN) + tid * 16);                     \
      GLOAD_LDS16(kstage + 24576, lds + (BN) + 4096 + tid * 16);              \
      GLOAD_LDS16(vstage,         lds + (BN) + 8192 + tid * 16);              \
      GLOAD_LDS16(vstage + 2048,  lds + (BN) + 12288 + tid * 16);             \
      kstage += 49152; vstage += 4096;                                        \
    }                                                                         \
    _Pragma("unroll")                                                         \
    for (int st = 0; st < 2; ++st) {                                          \
      f32x16 s = __builtin_amdgcn_mfma_f32_32x32x16_bf16(                     \
          *(const short8*)(lds + (BO) + st * 4096 + kaddr[0]), qf[0], zro, 0, 0, 0); \
      _Pragma("unroll")                                                       \
      for (int c = 1; c < 4; ++c)                                             \
        s = __builtin_amdgcn_mfma_f32_32x32x16_bf16(                          \
            *(const short8*)(lds + (BO) + st * 4096 + kaddr[c]), qf[c], s, 0, 0, 0); \
      short8 vf[2][2];                                                        \
      _Pragma("unroll")                                                       \
      for (int f = 0; f < 2; ++f)                                             \
        _Pragma("unroll")                                                     \
        for (int s2 = 0; s2 < 2; ++s2)                                        \
          vf[s2][f] = *(const short8*)(lds + (BO) + 8192 + st * 4096 + vaddr[s2][f]); \
      float p[16];                                                            \
      _Pragma("unroll")                                                       \
      for (int r = 0; r < 16; ++r) p[r] = exp2v(s[r]);                        \
      unsigned pw[8];                                                         \
      _Pragma("unroll")                                                       \
      for (int i = 0; i < 8; ++i) pw[i] = cvtpk(p[2 * i], p[2 * i + 1]);      \
      {                                                                       \
        unsigned x0 = pw[0], y0 = pw[2], x1 = pw[1], y1 = pw[3];              \
        asm("v_permlane32_swap_b32 %0, %1" : "+v"(x0), "+v"(y0));             \
        asm("v_permlane32_swap_b32 %0, %1" : "+v"(x1), "+v"(y1));             \
        union { u32x4 wv; short8 sv; } u;                                     \
        u.wv[0] = x0; u.wv[1] = x1; u.wv[2] = y0; u.wv[3] = y1;               \
        o0   = __builtin_amdgcn_mfma_f32_32x32x16_bf16(vf[0][0], u.sv, o0, 0, 0, 0); \
        o1   = __builtin_amdgcn_mfma_f32_32x32x16_bf16(vf[0][1], u.sv, o1, 0, 0, 0); \
        lacc = __builtin_amdgcn_mfma_f32_32x32x16_bf16(ones,     u.sv, lacc, 0, 0, 0); \
      }                                                                       \
      {                                                                       \
        unsigned x0 = pw[4], y0 = pw[6], x1 = pw[5], y1 = pw[7];              \
        asm("v_permlane32_swap_b32 %0, %1" : "+v"(x0), "+v"(y0));             \
        asm("v_permlane32_swap_b32 %0, %1" : "+v"(x1), "+v"(y1));             \
        union { u32x4 wv; short8 sv; } u;                                     \
        u.wv[0] = x0; u.wv[1] = x1; u.wv[2] = y0; u.wv[3] = y1;               \
        o0   = __builtin_amdgcn_mfma_f32_32x32x16_bf16(vf[1][0], u.sv, o0, 0, 0, 0); \
        o1   = __builtin_amdgcn_mfma_f32_32x32x16_bf16(vf[1][1], u.sv, o1, 0, 0, 0); \
        lacc = __builtin_amdgcn_mfma_f32_32x32x16_bf16(ones,     u.sv, lacc, 0, 0, 0); \
      }                                                                       \
    }                                                                         \
  }

  for (int tp = 0; tp < 8; ++tp) {
    ATTN_STEP(0, 16384, true);          // even iter 2tp: compute buf0, stage tile 2tp+1
    ATTN_STEP(16384, 0, (tp < 7));      // odd iter 2tp+1: compute buf1, stage tile 2tp+2
  }
#undef ATTN_STEP

  // epilogue: normalize, transpose via LDS, coalesced 16B stores
  __syncthreads();   // all waves done with staging buffers before reuse
  float inv = 1.f / lacc[0];
  char* lw = lds + w * 4608;
#pragma unroll
  for (int mg = 0; mg < 4; ++mg) {
    short4v t;
#pragma unroll
    for (int i = 0; i < 4; ++i) t[i] = (short)f2bf(o0[mg * 4 + i] * inv);
    *(short4v*)(lw + q32 * 144 + mg * 16 + hi * 8) = t;
#pragma unroll
    for (int i = 0; i < 4; ++i) t[i] = (short)f2bf(o1[mg * 4 + i] * inv);
    *(short4v*)(lw + q32 * 144 + 64 + mg * 16 + hi * 8) = t;
  }
  __syncthreads();
  const size_t obase = (size_t)(b * 1024 + qbase) * 768 + h * 64;
#pragma unroll
  for (int pp = 0; pp < 4; ++pp) {
    int chunk = pp * 64 + lane;      // 0..255
    int qr = chunk >> 3, cc = chunk & 7;
    short8 v = *(const short8*)(lw + qr * 144 + cc * 16);
    *(short8*)(og + obase + (size_t)qr * 768 + cc * 8) = v;
  }
}

// ---------------- launch ----------------
extern "C" void kernel_launch(void* const* d_in, const int* in_sizes, int n_in,
                              void* d_out, int out_size, void* d_ws, size_t ws_size,
                              hipStream_t stream) {
  const float* x  = (const float*)d_in[0];
  const float* Wq = (const float*)d_in[1];
  const float* bq = (const float*)d_in[2];
  const float* Wk = (const float*)d_in[3];
  const float* bk = (const float*)d_in[4];
  const float* Wp = (const float*)d_in[5];
  const float* bp = (const float*)d_in[6];
  float* out = (float*)d_out;
  char* ws = (char*)d_ws;

  const size_t XB = (size_t)16384 * 768 * 2;  // 25,165,824
  const size_t WB = (size_t)768 * 768 * 2;    //  1,179,648
  if (ws_size < 3 * XB + 3 * WB + 6144) return;

  unsigned short* xb  = (unsigned short*)(ws);
  unsigned short* qb  = (unsigned short*)(ws + XB);        // kb = qb + 16384*768 (adjacent)
  unsigned short* kb  = (unsigned short*)(ws + 2 * XB);
  unsigned short* wqb = (unsigned short*)(ws + 3 * XB);    // wkb adjacent -> stacked W
  unsigned short* wkb = (unsigned short*)(ws + 3 * XB + WB);
  unsigned short* wpb = (unsigned short*)(ws + 3 * XB + 2 * WB);
  float*          bqk = (float*)(ws + 3 * XB + 3 * WB);    // stacked bias [1536]
  unsigned short* ab  = xb;                    // x dead once q,k exist
  unsigned short* kTb = (unsigned short*)d_out; // 25MB scratch in d_out; dead before final GEMM

  k_prep<<<7878, 256, 0, stream>>>(x, Wq, Wk, Wp, bq, bk, xb, wqb, wkb, wpb, bqk);

  k_gemm_bt<2><<<dim3(128, 12), 256, 0, stream>>>(xb, wqb, bqk, qb, kTb, 16384, 1536, 768);
  k_attn<<<1536, 256, 0, stream>>>(qb, kb, kTb, ab);
  k_gemm_bt<0><<<dim3(128, 6), 256, 0, stream>>>(ab, wpb, bp, out, nullptr, 16384, 768, 768);
}

// Round 22
// 160.612 us; speedup vs baseline: 1.0159x; 1.0159x over previous
//
#include <hip/hip_runtime.h>
#include <hip/hip_bf16.h>

// AttentionSeparateQKV: B=16 N=1024 D=768 H=12 HD=64, V = K-projection (reference bug kept).
// R22 = R18 (best, 161.7us; R19/R20/R21 attn variants all regressed -> attn frozen at R18)
// + GEMM grid XCD swizzle (T1): each XCD owns a 16-row band and runs its 12 (or 6) column
// blocks consecutively -> x row-tile stays L2-hot across all column passes. Bijective,
// compile-time NY. Pure index remap; no sync-structure change.

#define DEV static __device__ __forceinline__

typedef __attribute__((ext_vector_type(8)))  short  short8;
typedef __attribute__((ext_vector_type(4)))  short  short4v;
typedef __attribute__((ext_vector_type(4)))  float  f32x4;
typedef __attribute__((ext_vector_type(16))) float  f32x16;
typedef __attribute__((ext_vector_type(4)))  unsigned short ushort4v;
typedef __attribute__((ext_vector_type(8)))  unsigned short ushort8v;
typedef __attribute__((ext_vector_type(4)))  unsigned int   u32x4;

#define QSCALE 0.180336880f   // 0.125 * log2(e): logits in log2 domain

DEV unsigned short f2bf(float x) {
  unsigned int u = __float_as_uint(x);
  u = u + 0x7fffu + ((u >> 16) & 1u);   // RNE, inputs finite
  return (unsigned short)(u >> 16);
}

DEV float exp2v(float x) {              // v_exp_f32: D = 2^S0 (pure, CSE-able)
  float r;
  asm("v_exp_f32 %0, %1" : "=v"(r) : "v"(x));
  return r;
}

DEV unsigned cvtpk(float a, float b) {  // lo = bf(a), hi = bf(b); RNE (R3-proven)
  unsigned r;
  asm("v_cvt_pk_bf16_f32 %0, %1, %2" : "=v"(r) : "v"(a), "v"(b));
  return r;
}

#define GLOAD_LDS16(g, l)                                                     \
  __builtin_amdgcn_global_load_lds(                                           \
      (const __attribute__((address_space(1))) void*)(g),                     \
      (__attribute__((address_space(3))) void*)(l), 16, 0, 0)

// ---------------- merged prep: x cvt (8/thread) + weight cvts + bias stack ----------------
// blocks [0,576): Wq; [576,1152): Wk; [1152,1728): Wp; [1728,1734): bqk; [1734,7878): x.
__global__ __launch_bounds__(256) void k_prep(const float* __restrict__ x,
                                              const float* __restrict__ Wq,
                                              const float* __restrict__ Wk,
                                              const float* __restrict__ Wp,
                                              const float* __restrict__ bq,
                                              const float* __restrict__ bk,
                                              unsigned short* __restrict__ xb,
                                              unsigned short* __restrict__ wqb,
                                              unsigned short* __restrict__ wkb,
                                              unsigned short* __restrict__ wpb,
                                              float* __restrict__ bqk) {
  int blk = blockIdx.x;
  if (blk < 1728) {
    const float* src = (blk < 576) ? Wq : (blk < 1152) ? Wk : Wp;
    unsigned short* dst = (blk < 576) ? wqb : (blk < 1152) ? wkb : wpb;
    int i = (blk % 576) * 256 + threadIdx.x;    // 576*256 = 768*768/4 exactly
    f32x4 v = *(const f32x4*)(src + (size_t)i * 4);
    ushort4v o;
    o[0] = f2bf(v[0]); o[1] = f2bf(v[1]); o[2] = f2bf(v[2]); o[3] = f2bf(v[3]);
    *(ushort4v*)(dst + (size_t)i * 4) = o;
  } else if (blk < 1734) {
    int i = (blk - 1728) * 256 + threadIdx.x;
    if (i < 768) bqk[i] = bq[i];
    else if (i < 1536) bqk[i] = bk[i - 768];
  } else {
    // x: 16384*768 f32 = 1,572,864 8-elem units = 6144 blocks exactly
    size_t i = (size_t)(blk - 1734) * 256 + threadIdx.x;
    const f32x4* src = (const f32x4*)(x + i * 8);
    f32x4 a = src[0], b4 = src[1];
    ushort8v o;
    o[0] = f2bf(a[0]);  o[1] = f2bf(a[1]);  o[2] = f2bf(a[2]);  o[3] = f2bf(a[3]);
    o[4] = f2bf(b4[0]); o[5] = f2bf(b4[1]); o[6] = f2bf(b4[2]); o[7] = f2bf(b4[3]);
    *(ushort8v*)(xb + i * 8) = o;
  }
}

// ---------------- GEMM: C = (A[M,K] * W[N,K]^T + bias[N]) ----------------
// bf16 A (R12-exact core). MODE 0: fp32 out (NY=6). MODE 2: QK-fused bf16 out (NY=12) —
// cols [0,768) -> Cv scaled QSCALE (Q, log2 domain); [768,1536) -> K buffer AND kT2.
// Grid XCD swizzle: linear block id l -> xcd = l&7 (dispatch round-robin), j = l>>3;
// row-block = xcd*(nx/8) + j/NY (16-row band per XCD), col-block = j%NY (consecutive).
template <int MODE>
__global__ __launch_bounds__(256) void k_gemm_bt(const unsigned short* __restrict__ A,
                                                 const unsigned short* __restrict__ W,
                                                 const float* __restrict__ bias,
                                                 void* __restrict__ Cv,
                                                 unsigned short* __restrict__ kT2g,
                                                 int M, int N, int K) {
  constexpr int NY = (MODE == 2) ? 12 : 6;
  __shared__ char lds[32768];
  char* ldsA = lds;
  char* ldsB = lds + 16384;
  const int tid  = threadIdx.x;
  const int wid  = tid >> 6;
  const int lane = tid & 63;
  const int l    = blockIdx.y * gridDim.x + blockIdx.x;   // dispatch-linear id
  const int xcd  = l & 7;
  const int j    = l >> 3;
  const int row0 = (xcd * (gridDim.x >> 3) + j / NY) * 128;
  const int col0 = (j % NY) * 128;
  const int wr = (wid >> 1) * 64;
  const int wc = (wid & 1) * 64;
  const int lr = lane & 15;
  const int lg = lane >> 4;

  f32x4 acc[4][4];
#pragma unroll
  for (int m = 0; m < 4; ++m)
#pragma unroll
    for (int n = 0; n < 4; ++n)
#pragma unroll
      for (int r = 0; r < 4; ++r) acc[m][n][r] = 0.f;

  for (int kt = 0; kt < K; kt += 64) {
    __syncthreads();
#pragma unroll
    for (int p = 0; p < 4; ++p) {
      int c = p * 256 + tid;               // 16B chunk id, 0..1023
      int r  = c >> 3;
      int cb = ((c & 7) << 4) ^ ((r & 7) << 4);
      const char* ga = (const char*)(A + (size_t)(row0 + r) * K + kt) + cb;
      GLOAD_LDS16(ga, ldsA + c * 16);
      const char* gb = (const char*)(W + (size_t)(col0 + r) * K + kt) + cb;
      GLOAD_LDS16(gb, ldsB + c * 16);
    }
    asm volatile("s_waitcnt vmcnt(0)" ::: "memory");
    __syncthreads();
#pragma unroll
    for (int kk = 0; kk < 2; ++kk) {
      short8 af[4], bf[4];
#pragma unroll
      for (int m = 0; m < 4; ++m) {
        int row = wr + m * 16 + lr;
        int a   = row * 128 + ((kk * 64 + lg * 16) ^ ((row & 7) << 4));
        af[m] = *(const short8*)(ldsA + a);
        int col = wc + m * 16 + lr;
        int b   = col * 128 + ((kk * 64 + lg * 16) ^ ((col & 7) << 4));
        bf[m] = *(const short8*)(ldsB + b);
      }
#pragma unroll
      for (int m = 0; m < 4; ++m)
#pragma unroll
        for (int n = 0; n < 4; ++n)
          acc[m][n] = __builtin_amdgcn_mfma_f32_16x16x32_bf16(af[m], bf[n], acc[m][n], 0, 0, 0);
    }
  }

  const int r0g = row0 + wr + lg * 4;
  const int c0g = col0 + wc + lr;
  float bv[4];
#pragma unroll
  for (int n = 0; n < 4; ++n) bv[n] = bias[c0g + n * 16];

  if constexpr (MODE == 2) {
    const bool kh = (col0 >= 768);
    unsigned short* dst = (unsigned short*)Cv + (kh ? ((size_t)16384 * 768 - 768) : 0);
    const float sc = kh ? 1.0f : QSCALE;
#pragma unroll
    for (int m = 0; m < 4; ++m)
#pragma unroll
      for (int n = 0; n < 4; ++n) {
        ushort4v t4;
#pragma unroll
        for (int r = 0; r < 4; ++r) {
          float v = (acc[m][n][r] + bv[n]) * sc;
          unsigned short bfv = f2bf(v);
          dst[(size_t)(r0g + m * 16 + r) * 768 + (c0g + n * 16)] = bfv;
          t4[r] = bfv;
        }
        if (kh) {
          // transpose-fused kT2 store: rows rowb..rowb+3 (n dim), col = head dim
          int hd2  = c0g + n * 16 - 768;     // 0..767: h = hd2>>6, hd = hd2&63
          int rowb = r0g + m * 16;           // multiple of 4 -> nn&31 stays in-block
          int b_ = rowb >> 10, nn = rowb & 1023;
          size_t kbase = ((((size_t)(b_ * 12 + (hd2 >> 6)) * 32 + (nn >> 5)) * 64
                           + (hd2 & 63)) * 32 + (nn & 31));
          *(ushort4v*)(kT2g + kbase) = t4;
        }
      }
  } else {
#pragma unroll
    for (int m = 0; m < 4; ++m)
#pragma unroll
      for (int n = 0; n < 4; ++n)
#pragma unroll
        for (int r = 0; r < 4; ++r) {
          float v = acc[m][n][r] + bv[n];
          ((float*)Cv)[(size_t)(r0g + m * 16 + r) * N + (c0g + n * 16)] = v;
        }
  }
}

// ---------------- Flash attention (V = K; q pre-scaled by 0.125*log2e) ----------------
// R18-exact: KVBLK=64, per iteration stage 2 K-tiles + 2 V-tiles (16KB, 4 gloads),
// compute both subtiles between barriers. 2-phase dbuf (32KB LDS), vmcnt(0)+syncthreads.
// Un-normalized p = 2^s; lsum via ones-MFMA; zero-C QK^T.
__global__ __launch_bounds__(256) void k_attn(const unsigned short* __restrict__ qg,
                                              const unsigned short* __restrict__ kg,
                                              const unsigned short* __restrict__ kT2,
                                              unsigned short* __restrict__ og) {
  __shared__ char lds[32768];           // 2 x 16KB staging dbuf; epilogue reuses [0,18432)
  const int tid  = threadIdx.x;
  const int w    = tid >> 6;
  const int lane = tid & 63;
  const int q32  = lane & 31;
  const int hi   = lane >> 5;
  // XCD swizzle: 8 qc-blocks of each bh land on one XCD (grid 1536 = 8*192)
  const int blk  = (blockIdx.x & 7) * 192 + (blockIdx.x >> 3);
  const int qc   = blk & 7;
  const int bh   = blk >> 3;
  const int h = bh % 12, b = bh / 12;
  const int qbase = qc * 128 + w * 32;

  const unsigned short* Qp = qg + (size_t)(b * 1024 + qbase + q32) * 768 + h * 64;
  short8 qf[4];
#pragma unroll
  for (int c = 0; c < 4; ++c) qf[c] = *(const short8*)(Qp + c * 16 + hi * 8);

  // ones A-frag for the lsum MFMA (bf16 1.0 = 0x3F80)
  short8 ones;
#pragma unroll
  for (int j = 0; j < 8; ++j) ones[j] = (short)0x3F80;

  // staging source pointers (k-row tile 0 / v tile 0)
  // K subtile st of iter t: ksrc + t*49152 + st*24576 (rows t*64+st*32+sr)
  // V subtile st of iter t: vsrc + t*4096  + st*2048  (kT2 tile 2t+st)
  const int sr = tid >> 3, sp = tid & 7;                     // Kt: row, phys slot
  const unsigned short* ksrc = kg + (size_t)(b * 1024 + sr) * 768 + h * 64 + ((sp ^ (sr & 7)) << 3);
  const int vh = tid >> 2, vp = tid & 3;                     // Vt: hd, phys slot
  const unsigned short* vsrc = kT2 + (size_t)bh * 65536 + (size_t)vh * 32 + ((vp ^ ((vh >> 1) & 3)) << 3);

  f32x16 o0, o1, lacc, zro;
#pragma unroll
  for (int r = 0; r < 16; ++r) { o0[r] = 0.f; o1[r] = 0.f; lacc[r] = 0.f; zro[r] = 0.f; }

  // prologue: stage iter 0 (K0,K1,V0,V1) into buf 0
  GLOAD_LDS16(ksrc,          lds + tid * 16);
  GLOAD_LDS16(ksrc + 24576,  lds + 4096 + tid * 16);
  GLOAD_LDS16(vsrc,          lds + 8192 + tid * 16);
  GLOAD_LDS16(vsrc + 2048,   lds + 12288 + tid * 16);

  const int kfo0 = q32 * 128;
  const int vswz = (q32 >> 1) & 3;

  for (int t = 0; t < 16; ++t) {
    const int bo = (t & 1) << 14;
    asm volatile("s_waitcnt vmcnt(0)" ::: "memory");
    __syncthreads();
    if (t + 1 < 16) {
      const int bn = bo ^ 16384;
      const unsigned short* kn = ksrc + (size_t)(t + 1) * 49152;
      const unsigned short* vn = vsrc + (size_t)(t + 1) * 4096;
      GLOAD_LDS16(kn,         lds + bn + tid * 16);
      GLOAD_LDS16(kn + 24576, lds + bn + 4096 + tid * 16);
      GLOAD_LDS16(vn,         lds + bn + 8192 + tid * 16);
      GLOAD_LDS16(vn + 2048,  lds + bn + 12288 + tid * 16);
    }

#pragma unroll
    for (int st = 0; st < 2; ++st) {
      const int kb0 = bo + st * 4096 + kfo0;
      const int vb0 = bo + 8192 + st * 4096;

      // QK^T: A = K rows (lane: row q32, k-cols c*16+hi*8..+7); C starts from zro
      short8 kf0 = *(const short8*)(lds + kb0 + ((hi ^ (q32 & 7)) << 4));
      f32x16 s = __builtin_amdgcn_mfma_f32_32x32x16_bf16(kf0, qf[0], zro, 0, 0, 0);
#pragma unroll
      for (int c = 1; c < 4; ++c) {
        short8 kf = *(const short8*)(lds + kb0 + (((c * 2 + hi) ^ (q32 & 7)) << 4));
        s = __builtin_amdgcn_mfma_f32_32x32x16_bf16(kf, qf[c], s, 0, 0, 0);
      }

      // V^T frags: lane: hd = f*32+q32, k = s2*16+hi*8..+7
      short8 vf[2][2];
#pragma unroll
      for (int f = 0; f < 2; ++f)
#pragma unroll
        for (int s2 = 0; s2 < 2; ++s2)
          vf[s2][f] = *(const short8*)(lds + vb0 + (f * 32 + q32) * 64 +
                                       (((s2 * 2 + hi) ^ vswz) << 4));

      // un-normalized softmax: p = 2^s (bounded; shift-invariance cancels the offset)
      float p[16];
#pragma unroll
      for (int r = 0; r < 16; ++r) p[r] = exp2v(s[r]);

      // pack P to bf16 words: pw[i] = {bf(p[2i]) lo, bf(p[2i+1]) hi}
      unsigned pw[8];
#pragma unroll
      for (int i = 0; i < 8; ++i) pw[i] = cvtpk(p[2 * i], p[2 * i + 1]);

      // s2 = 0: B-frag words = swap(pw0,pw2), swap(pw1,pw3)
      {
        unsigned x0 = pw[0], y0 = pw[2], x1 = pw[1], y1 = pw[3];
        asm("v_permlane32_swap_b32 %0, %1" : "+v"(x0), "+v"(y0));
        asm("v_permlane32_swap_b32 %0, %1" : "+v"(x1), "+v"(y1));
        union { u32x4 wv; short8 sv; } u;
        u.wv[0] = x0; u.wv[1] = x1; u.wv[2] = y0; u.wv[3] = y1;
        o0   = __builtin_amdgcn_mfma_f32_32x32x16_bf16(vf[0][0], u.sv, o0, 0, 0, 0);
        o1   = __builtin_amdgcn_mfma_f32_32x32x16_bf16(vf[0][1], u.sv, o1, 0, 0, 0);
        lacc = __builtin_amdgcn_mfma_f32_32x32x16_bf16(ones,     u.sv, lacc, 0, 0, 0);
      }
      // s2 = 1
      {
        unsigned x0 = pw[4], y0 = pw[6], x1 = pw[5], y1 = pw[7];
        asm("v_permlane32_swap_b32 %0, %1" : "+v"(x0), "+v"(y0));
        asm("v_permlane32_swap_b32 %0, %1" : "+v"(x1), "+v"(y1));
        union { u32x4 wv; short8 sv; } u;
        u.wv[0] = x0; u.wv[1] = x1; u.wv[2] = y0; u.wv[3] = y1;
        o0   = __builtin_amdgcn_mfma_f32_32x32x16_bf16(vf[1][0], u.sv, o0, 0, 0, 0);
        o1   = __builtin_amdgcn_mfma_f32_32x32x16_bf16(vf[1][1], u.sv, o1, 0, 0, 0);
        lacc = __builtin_amdgcn_mfma_f32_32x32x16_bf16(ones,     u.sv, lacc, 0, 0, 0);
      }
    }
  }

  // epilogue: normalize, transpose via LDS, coalesced 16B stores
  __syncthreads();   // all waves done with staging buffers before reuse
  float inv = 1.f / lacc[0];
  char* lw = lds + w * 4608;
#pragma unroll
  for (int mg = 0; mg < 4; ++mg) {
    short4v t;
#pragma unroll
    for (int i = 0; i < 4; ++i) t[i] = (short)f2bf(o0[mg * 4 + i] * inv);
    *(short4v*)(lw + q32 * 144 + mg * 16 + hi * 8) = t;
#pragma unroll
    for (int i = 0; i < 4; ++i) t[i] = (short)f2bf(o1[mg * 4 + i] * inv);
    *(short4v*)(lw + q32 * 144 + 64 + mg * 16 + hi * 8) = t;
  }
  __syncthreads();
  const size_t obase = (size_t)(b * 1024 + qbase) * 768 + h * 64;
#pragma unroll
  for (int pp = 0; pp < 4; ++pp) {
    int chunk = pp * 64 + lane;      // 0..255
    int qr = chunk >> 3, cc = chunk & 7;
    short8 v = *(const short8*)(lw + qr * 144 + cc * 16);
    *(short8*)(og + obase + (size_t)qr * 768 + cc * 8) = v;
  }
}

// ---------------- launch ----------------
extern "C" void kernel_launch(void* const* d_in, const int* in_sizes, int n_in,
                              void* d_out, int out_size, void* d_ws, size_t ws_size,
                              hipStream_t stream) {
  const float* x  = (const float*)d_in[0];
  const float* Wq = (const float*)d_in[1];
  const float* bq = (const float*)d_in[2];
  const float* Wk = (const float*)d_in[3];
  const float* bk = (const float*)d_in[4];
  const float* Wp = (const float*)d_in[5];
  const float* bp = (const float*)d_in[6];
  float* out = (float*)d_out;
  char* ws = (char*)d_ws;

  const size_t XB = (size_t)16384 * 768 * 2;  // 25,165,824
  const size_t WB = (size_t)768 * 768 * 2;    //  1,179,648
  if (ws_size < 3 * XB + 3 * WB + 6144) return;

  unsigned short* xb  = (unsigned short*)(ws);
  unsigned short* qb  = (unsigned short*)(ws + XB);        // kb = qb + 16384*768 (adjacent)
  unsigned short* kb  = (unsigned short*)(ws + 2 * XB);
  unsigned short* wqb = (unsigned short*)(ws + 3 * XB);    // wkb adjacent -> stacked W
  unsigned short* wkb = (unsigned short*)(ws + 3 * XB + WB);
  unsigned short* wpb = (unsigned short*)(ws + 3 * XB + 2 * WB);
  float*          bqk = (float*)(ws + 3 * XB + 3 * WB);    // stacked bias [1536]
  unsigned short* ab  = xb;                    // x dead once q,k exist
  unsigned short* kTb = (unsigned short*)d_out; // 25MB scratch in d_out; dead before final GEMM

  k_prep<<<7878, 256, 0, stream>>>(x, Wq, Wk, Wp, bq, bk, xb, wqb, wkb, wpb, bqk);

  k_gemm_bt<2><<<dim3(128, 12), 256, 0, stream>>>(xb, wqb, bqk, qb, kTb, 16384, 1536, 768);
  k_attn<<<1536, 256, 0, stream>>>(qb, kb, kTb, ab);
  k_gemm_bt<0><<<dim3(128, 6), 256, 0, stream>>>(ab, wpb, bp, out, nullptr, 16384, 768, 768);
}